// Round 1
// baseline (972.185 us; speedup 1.0000x reference)
//
#include <hip/hip_runtime.h>

#define N_NODES 10242
#define NNZ_E   71694
#define BT      32      // B*T
#define C_IN    16
#define K_S     20
#define C_OUT   32
#define F       512     // C_IN * BT

// ---------------- CSR build ----------------

__global__ void zero_kernel(int* p, int n) {
    int i = blockIdx.x * blockDim.x + threadIdx.x;
    if (i < n) p[i] = 0;
}

__global__ void count_kernel(const int* __restrict__ erow, int* cnt) {
    int e = blockIdx.x * blockDim.x + threadIdx.x;
    if (e < NNZ_E) atomicAdd(&cnt[erow[e]], 1);
}

// single block, 256 threads: exclusive scan of cnt[0..N-1] -> row_ptr[0..N], copy to cursor
__global__ void scan_kernel(const int* __restrict__ cnt, int* row_ptr, int* cursor) {
    const int T = 256;
    const int chunk = (N_NODES + T - 1) / T;  // 41
    __shared__ int part[T];
    int t = threadIdx.x;
    int base = t * chunk;
    int s = 0;
    for (int i = 0; i < chunk; ++i) {
        int idx = base + i;
        if (idx < N_NODES) s += cnt[idx];
    }
    part[t] = s;
    __syncthreads();
    // Hillis-Steele inclusive scan
    for (int off = 1; off < T; off <<= 1) {
        int v = (t >= off) ? part[t - off] : 0;
        __syncthreads();
        part[t] += v;
        __syncthreads();
    }
    int run = (t == 0) ? 0 : part[t - 1];
    for (int i = 0; i < chunk; ++i) {
        int idx = base + i;
        if (idx < N_NODES) {
            row_ptr[idx] = run;
            cursor[idx]  = run;
            run += cnt[idx];
        }
    }
    if (base <= N_NODES && N_NODES < base + chunk) {
        row_ptr[N_NODES] = run;   // == NNZ
    }
}

__global__ void scatter_kernel(const int* __restrict__ erow, const int* __restrict__ ecol,
                               const float* __restrict__ eval,
                               int* cursor, int* __restrict__ ccol, float* __restrict__ cval) {
    int e = blockIdx.x * blockDim.x + threadIdx.x;
    if (e < NNZ_E) {
        int r = erow[e];
        int p = atomicAdd(&cursor[r], 1);
        ccol[p] = ecol[e];
        cval[p] = eval[e];
    }
}

// ---------------- transform x -> T0 + k=0 projection ----------------
// x layout: [(bt*N + n)*C_IN + c]; T0 row layout: col = c*BT + bt
// out layout: [(bt*N + n)*C_OUT + cout], written with '=' (covers all outputs)

__global__ __launch_bounds__(128) void transform_kernel(
        const float* __restrict__ x, const float* __restrict__ W,
        float* __restrict__ buf0, float* __restrict__ out) {
    int n = blockIdx.x;
    int t = threadIdx.x;
    __shared__ float row[F];
    __shared__ float Ws[C_OUT * C_IN];

    // load W slice for k=0: Ws[cout*16 + c] = W[cout*320 + c*20 + 0]
    for (int j = t; j < C_OUT * C_IN; j += 128) {
        int cout = j >> 4, c = j & 15;
        Ws[j] = W[cout * (C_IN * K_S) + c * K_S + 0];
    }
    // gather x into [c*32 + bt] layout
    #pragma unroll
    for (int j = 0; j < 4; ++j) {
        int idx = t + 128 * j;
        int bt = idx >> 4, c = idx & 15;
        row[c * BT + bt] = x[((size_t)bt * N_NODES + n) * C_IN + c];
    }
    __syncthreads();

    // write T0 row (coalesced float4)
    ((float4*)(buf0 + (size_t)n * F))[t] = ((const float4*)row)[t];

    // k=0 projection: out[bt][n][cout] = sum_c row[c*32+bt] * Ws[cout][c]
    int bt = t & 31;
    int coutBase = (t >> 5) * 8;
    float acc[8];
    #pragma unroll
    for (int j = 0; j < 8; ++j) acc[j] = 0.f;
    #pragma unroll
    for (int c = 0; c < C_IN; ++c) {
        float yv = row[c * BT + bt];
        #pragma unroll
        for (int j = 0; j < 8; ++j)
            acc[j] += yv * Ws[(coutBase + j) * C_IN + c];
    }
    float* op = out + ((size_t)bt * N_NODES + n) * C_OUT + coutBase;
    #pragma unroll
    for (int j = 0; j < 8; ++j) op[j] = acc[j];
}

// ---------------- Chebyshev step + fused projection accumulate ----------------
// y = alpha * (L @ srcB)[n] + beta * srcA[n];  dst[n] = y;  out += proj_k(y)

__global__ __launch_bounds__(128) void spmm_step_kernel(
        const float* __restrict__ srcB, const float* __restrict__ srcA,
        float* __restrict__ dst,
        const int* __restrict__ row_ptr, const int* __restrict__ ccol,
        const float* __restrict__ cval,
        const float* __restrict__ W, int k, float alpha, float beta,
        float* __restrict__ out) {
    int n = blockIdx.x;
    int t = threadIdx.x;
    __shared__ float row[F];
    __shared__ float Ws[C_OUT * C_IN];

    for (int j = t; j < C_OUT * C_IN; j += 128) {
        int cout = j >> 4, c = j & 15;
        Ws[j] = W[cout * (C_IN * K_S) + c * K_S + k];
    }

    int start = row_ptr[n];
    int end   = row_ptr[n + 1];
    float4 acc = make_float4(0.f, 0.f, 0.f, 0.f);
    for (int e = start; e < end; ++e) {
        int col = ccol[e];
        float v = cval[e];
        float4 b = ((const float4*)(srcB + (size_t)col * F))[t];
        acc.x += v * b.x; acc.y += v * b.y; acc.z += v * b.z; acc.w += v * b.w;
    }
    float4 y;
    if (beta != 0.f) {
        float4 a = ((const float4*)(srcA + (size_t)n * F))[t];
        y.x = alpha * acc.x + beta * a.x;
        y.y = alpha * acc.y + beta * a.y;
        y.z = alpha * acc.z + beta * a.z;
        y.w = alpha * acc.w + beta * a.w;
    } else {
        y.x = alpha * acc.x; y.y = alpha * acc.y;
        y.z = alpha * acc.z; y.w = alpha * acc.w;
    }
    ((float4*)(dst + (size_t)n * F))[t] = y;
    ((float4*)row)[t] = y;
    __syncthreads();

    // projection accumulate
    int bt = t & 31;
    int coutBase = (t >> 5) * 8;
    float pacc[8];
    #pragma unroll
    for (int j = 0; j < 8; ++j) pacc[j] = 0.f;
    #pragma unroll
    for (int c = 0; c < C_IN; ++c) {
        float yv = row[c * BT + bt];
        #pragma unroll
        for (int j = 0; j < 8; ++j)
            pacc[j] += yv * Ws[(coutBase + j) * C_IN + c];
    }
    float* op = out + ((size_t)bt * N_NODES + n) * C_OUT + coutBase;
    #pragma unroll
    for (int j = 0; j < 8; ++j) op[j] += pacc[j];
}

// ---------------- host launch ----------------

extern "C" void kernel_launch(void* const* d_in, const int* in_sizes, int n_in,
                              void* d_out, int out_size, void* d_ws, size_t ws_size,
                              hipStream_t stream) {
    const float* x    = (const float*)d_in[0];
    const int*   erow = (const int*)  d_in[1];
    const int*   ecol = (const int*)  d_in[2];
    const float* eval = (const float*)d_in[3];
    const float* W    = (const float*)d_in[4];
    float* out = (float*)d_out;

    char* ws = (char*)d_ws;
    size_t o = 0;
    auto alloc = [&](size_t bytes) -> char* {
        o = (o + 511) & ~(size_t)511;
        char* r = ws + o;
        o += bytes;
        return r;
    };
    int*   cnt     = (int*)  alloc((size_t)N_NODES * 4);
    int*   row_ptr = (int*)  alloc((size_t)(N_NODES + 1) * 4);
    int*   cursor  = (int*)  alloc((size_t)N_NODES * 4);
    int*   ccol    = (int*)  alloc((size_t)NNZ_E * 4);
    float* cval    = (float*)alloc((size_t)NNZ_E * 4);
    float* buf[3];
    buf[0] = (float*)alloc((size_t)N_NODES * F * 4);
    buf[1] = (float*)alloc((size_t)N_NODES * F * 4);
    buf[2] = (float*)alloc((size_t)N_NODES * F * 4);

    // CSR build
    zero_kernel<<<(N_NODES + 255) / 256, 256, 0, stream>>>(cnt, N_NODES);
    count_kernel<<<(NNZ_E + 255) / 256, 256, 0, stream>>>(erow, cnt);
    scan_kernel<<<1, 256, 0, stream>>>(cnt, row_ptr, cursor);
    scatter_kernel<<<(NNZ_E + 255) / 256, 256, 0, stream>>>(erow, ecol, eval, cursor, ccol, cval);

    // T0 + k=0 projection
    transform_kernel<<<N_NODES, 128, 0, stream>>>(x, W, buf[0], out);

    // k = 1: T1 = L @ T0              (alpha=1, beta=0)
    // k>=2:  Tk = 2 L @ T_{k-1} - T_{k-2}
    for (int k = 1; k < K_S; ++k) {
        const float* srcB = buf[(k - 1) % 3];
        const float* srcA = (k >= 2) ? buf[(k - 2) % 3] : buf[0];  // unused when beta==0
        float* dstp = buf[k % 3];
        float alpha = (k == 1) ? 1.f : 2.f;
        float beta  = (k == 1) ? 0.f : -1.f;
        spmm_step_kernel<<<N_NODES, 128, 0, stream>>>(
            srcB, srcA, dstp, row_ptr, ccol, cval, W, k, alpha, beta, out);
    }
}

// Round 2
// 770.968 us; speedup vs baseline: 1.2610x; 1.2610x over previous
//
#include <hip/hip_runtime.h>

#define N_NODES 10242
#define NNZ_E   71694
#define BT      32      // B*T
#define C_IN    16
#define K_S     20
#define C_OUT   32
#define F       512     // BT * C_IN
#define BUF_FLOATS ((size_t)N_NODES * F)          // 5,243,904 floats
#define BUF_BYTES  (BUF_FLOATS * 4)               // ~21 MB

// ---------------- CSR build ----------------

__global__ void zero_kernel(int* p, int n) {
    int i = blockIdx.x * blockDim.x + threadIdx.x;
    if (i < n) p[i] = 0;
}

__global__ void count_kernel(const int* __restrict__ erow, int* cnt) {
    int e = blockIdx.x * blockDim.x + threadIdx.x;
    if (e < NNZ_E) atomicAdd(&cnt[erow[e]], 1);
}

__global__ void scan_kernel(const int* __restrict__ cnt, int* row_ptr, int* cursor) {
    const int T = 256;
    const int chunk = (N_NODES + T - 1) / T;  // 41
    __shared__ int part[T];
    int t = threadIdx.x;
    int base = t * chunk;
    int s = 0;
    for (int i = 0; i < chunk; ++i) {
        int idx = base + i;
        if (idx < N_NODES) s += cnt[idx];
    }
    part[t] = s;
    __syncthreads();
    for (int off = 1; off < T; off <<= 1) {
        int v = (t >= off) ? part[t - off] : 0;
        __syncthreads();
        part[t] += v;
        __syncthreads();
    }
    int run = (t == 0) ? 0 : part[t - 1];
    for (int i = 0; i < chunk; ++i) {
        int idx = base + i;
        if (idx < N_NODES) {
            row_ptr[idx] = run;
            cursor[idx]  = run;
            run += cnt[idx];
        }
    }
    if (base <= N_NODES && N_NODES < base + chunk) {
        row_ptr[N_NODES] = run;
    }
}

__global__ void scatter_kernel(const int* __restrict__ erow, const int* __restrict__ ecol,
                               const float* __restrict__ eval,
                               int* cursor, int* __restrict__ ccol, float* __restrict__ cval) {
    int e = blockIdx.x * blockDim.x + threadIdx.x;
    if (e < NNZ_E) {
        int r = erow[e];
        int p = atomicAdd(&cursor[r], 1);
        ccol[p] = ecol[e];
        cval[p] = eval[e];
    }
}

// Wt[k][c][cout] = W[cout][c*K_S + k]   (wave-uniform weight tiles for proj)
__global__ void wt_kernel(const float* __restrict__ W, float* __restrict__ Wt) {
    int i = blockIdx.x * blockDim.x + threadIdx.x;  // K_S*C_IN*C_OUT = 10240
    if (i < K_S * C_IN * C_OUT) {
        int cout = i & 31;
        int c    = (i >> 5) & 15;
        int k    = i >> 9;
        Wt[i] = W[cout * (C_IN * K_S) + c * K_S + k];
    }
}

// ---------------- transform: x -> T0, layout T[n][bt*16+c] ----------------

__global__ __launch_bounds__(128) void transform_kernel(
        const float* __restrict__ x, float* __restrict__ T0) {
    int n = blockIdx.x;
    int t = threadIdx.x;              // float4 chunk: floats 4t..4t+3
    int bt = t >> 2;
    int c0 = (t & 3) * 4;
    float4 v = *(const float4*)(x + ((size_t)bt * N_NODES + n) * C_IN + c0);
    *(float4*)(T0 + (size_t)n * F + bt * C_IN + c0) = v;
}

// ---------------- Chebyshev step: dst = alpha * L @ srcB + beta * srcA -----

__global__ __launch_bounds__(128) void spmm_step_kernel(
        const float* __restrict__ srcB, const float* __restrict__ srcA,
        float* __restrict__ dst,
        const int* __restrict__ row_ptr, const int* __restrict__ ccol,
        const float* __restrict__ cval, float alpha, float beta) {
    int n = blockIdx.x;
    int q = threadIdx.x;              // float4 index within the 512-float row
    int start = row_ptr[n];
    int end   = row_ptr[n + 1];
    float4 acc0 = make_float4(0.f, 0.f, 0.f, 0.f);
    float4 acc1 = make_float4(0.f, 0.f, 0.f, 0.f);
    int e = start;
    for (; e + 1 < end; e += 2) {
        int   col0 = ccol[e],  col1 = ccol[e + 1];
        float v0   = cval[e],  v1   = cval[e + 1];
        float4 b0 = ((const float4*)(srcB + (size_t)col0 * F))[q];
        float4 b1 = ((const float4*)(srcB + (size_t)col1 * F))[q];
        acc0.x += v0 * b0.x; acc0.y += v0 * b0.y; acc0.z += v0 * b0.z; acc0.w += v0 * b0.w;
        acc1.x += v1 * b1.x; acc1.y += v1 * b1.y; acc1.z += v1 * b1.z; acc1.w += v1 * b1.w;
    }
    if (e < end) {
        int   col = ccol[e];
        float v   = cval[e];
        float4 b = ((const float4*)(srcB + (size_t)col * F))[q];
        acc0.x += v * b.x; acc0.y += v * b.y; acc0.z += v * b.z; acc0.w += v * b.w;
    }
    float4 a = ((const float4*)(srcA + (size_t)n * F))[q];
    float4 y;
    y.x = alpha * (acc0.x + acc1.x) + beta * a.x;
    y.y = alpha * (acc0.y + acc1.y) + beta * a.y;
    y.z = alpha * (acc0.z + acc1.z) + beta * a.z;
    y.w = alpha * (acc0.w + acc1.w) + beta * a.w;
    ((float4*)(dst + (size_t)n * F))[q] = y;
}

// ---------------- projection pass over a chunk of k values ----------------
// out[(bt*N+n)*32 + cout] (+)= sum_{j<kcnt} sum_c T_{k0+j}[n][bt*16+c] * Wt[k0+j][c][cout]

__global__ __launch_bounds__(256) void proj_kernel(
        const float* __restrict__ bufbase, int R, int k0, int kcnt,
        const float* __restrict__ Wt, float* __restrict__ out, int accumulate) {
    int g = blockIdx.x * 256 + threadIdx.x;   // row id over N*BT
    if (g >= N_NODES * BT) return;
    int bt = g & 31;
    int n  = g >> 5;

    float acc[C_OUT];
    #pragma unroll
    for (int co = 0; co < C_OUT; ++co) acc[co] = 0.f;

    for (int j = 0; j < kcnt; ++j) {
        int k = k0 + j;
        const float* Trow = bufbase + (size_t)(k % R) * BUF_FLOATS
                          + (size_t)n * F + bt * C_IN;
        float yv[C_IN];
        #pragma unroll
        for (int qq = 0; qq < 4; ++qq)
            *(float4*)(yv + 4 * qq) = ((const float4*)Trow)[qq];
        const float* wk = Wt + (size_t)k * C_IN * C_OUT;
        #pragma unroll
        for (int c = 0; c < C_IN; ++c) {
            #pragma unroll
            for (int co = 0; co < C_OUT; ++co)
                acc[co] += yv[c] * wk[c * C_OUT + co];
        }
    }

    float* op = out + ((size_t)bt * N_NODES + n) * C_OUT;
    if (accumulate) {
        #pragma unroll
        for (int co = 0; co < C_OUT; ++co) acc[co] += op[co];
    }
    #pragma unroll
    for (int qq = 0; qq < 8; ++qq)
        *(float4*)(op + 4 * qq) = *(float4*)(acc + 4 * qq);
}

// ---------------- host launch ----------------

extern "C" void kernel_launch(void* const* d_in, const int* in_sizes, int n_in,
                              void* d_out, int out_size, void* d_ws, size_t ws_size,
                              hipStream_t stream) {
    const float* x    = (const float*)d_in[0];
    const int*   erow = (const int*)  d_in[1];
    const int*   ecol = (const int*)  d_in[2];
    const float* eval = (const float*)d_in[3];
    const float* W    = (const float*)d_in[4];
    float* out = (float*)d_out;

    char* ws = (char*)d_ws;
    size_t o = 0;
    auto alloc = [&](size_t bytes) -> char* {
        o = (o + 511) & ~(size_t)511;
        char* r = ws + o;
        o += bytes;
        return r;
    };
    int*   cnt     = (int*)  alloc((size_t)N_NODES * 4);
    int*   row_ptr = (int*)  alloc((size_t)(N_NODES + 1) * 4);
    int*   cursor  = (int*)  alloc((size_t)N_NODES * 4);
    int*   ccol    = (int*)  alloc((size_t)NNZ_E * 4);
    float* cval    = (float*)alloc((size_t)NNZ_E * 4);
    float* Wt      = (float*)alloc((size_t)K_S * C_IN * C_OUT * 4);
    o = (o + 511) & ~(size_t)511;

    // ring of R T-buffers, sized from remaining workspace (R in [3, 9])
    size_t remain = (ws_size > o) ? (ws_size - o) : 0;
    int R = (int)(remain / BUF_BYTES);
    if (R > 9) R = 9;
    if (R < 3) R = 3;   // round-1 usage proved ws >= ~64 MB
    float* bufbase = (float*)alloc((size_t)R * BUF_BYTES);
    auto buf = [&](int k) -> float* { return bufbase + (size_t)(k % R) * BUF_FLOATS; };
    int chunk = R - 2;
    if (chunk > 7) chunk = 7;

    // CSR build + weight transpose
    zero_kernel<<<(N_NODES + 255) / 256, 256, 0, stream>>>(cnt, N_NODES);
    count_kernel<<<(NNZ_E + 255) / 256, 256, 0, stream>>>(erow, cnt);
    scan_kernel<<<1, 256, 0, stream>>>(cnt, row_ptr, cursor);
    scatter_kernel<<<(NNZ_E + 255) / 256, 256, 0, stream>>>(erow, ecol, eval, cursor, ccol, cval);
    wt_kernel<<<(K_S * C_IN * C_OUT + 255) / 256, 256, 0, stream>>>(W, Wt);

    const int proj_blocks = (N_NODES * BT + 255) / 256;
    int c0 = 0;
    bool first = true;
    auto maybe_pass = [&](int k_done) {
        int cnt_k = K_S - c0;
        if (cnt_k > chunk) cnt_k = chunk;
        if (k_done == c0 + cnt_k - 1) {
            proj_kernel<<<proj_blocks, 256, 0, stream>>>(
                bufbase, R, c0, cnt_k, Wt, out, first ? 0 : 1);
            first = false;
            c0 += cnt_k;
        }
    };

    // T0
    transform_kernel<<<N_NODES, 128, 0, stream>>>(x, buf(0));
    maybe_pass(0);

    // T1 = L T0 ; Tk = 2 L T_{k-1} - T_{k-2}
    for (int k = 1; k < K_S; ++k) {
        const float* srcB = buf(k - 1);
        const float* srcA = (k >= 2) ? buf(k - 2) : buf(k - 1);  // beta=0 when k==1
        float alpha = (k == 1) ? 1.f : 2.f;
        float beta  = (k == 1) ? 0.f : -1.f;
        spmm_step_kernel<<<N_NODES, 128, 0, stream>>>(
            srcB, srcA, buf(k), row_ptr, ccol, cval, alpha, beta);
        maybe_pass(k);
    }
}